// Round 1
// baseline (227.524 us; speedup 1.0000x reference)
//
#include <hip/hip_runtime.h>

// EMA along T for pos_seq (B=64, T=8192, C=51) fp32.
// y[b,0,c] = x[b,0,c];  y[b,t,c] = 0.25*x[b,t,c] + 0.75*y[b,t-1,c]
//
// R7: barrier-free register-resident scan. R6 post-mortem: VALUBusy 9%,
// BW 2.65 TB/s (33%), occupancy 37%, MfmaUtil 0 -> latency-bound
// bulk-synchronous structure, not a BW wall. The LDS tile existed only to
// transpose coalesced loads into t-chains; its 3 barriers + vmcnt(0) drains
// kept synchronizing all resident blocks into the same phase, idling HBM.
//
// New decomposition: 51 channels = 17 threads x 3 channels. Each thread owns
// (b, chunk, c-triple) and walks t serially, fully in registers:
//   - loads/stores are 12 B/lane (dwordx2 + dword), 17 lanes cover one 204 B
//     row contiguously -> coalesced streaming, no transpose, no LDS, no
//     barriers, no tail threads.
//   - 48-row halo warm-up (0.75^48 ~ 1e-6, same approximation as the proven
//     R6 kernel). chunk 0: acc = x[0], then the uniform EMA step yields
//     y0 = 0.25*x0 + 0.75*x0 = x0 exactly (1 ulp).
//   - chain is 1 fma/step: acc = fma(0.75, acc, 0.25*x).
//   - explicit depth-2 row prefetch; 2176 single-wave blocks = 8.5 waves/CU
//     -> ~13 KB/CU of loads in flight, enough for 6.3 TB/s at ~900 cy HBM
//     latency. Every branch is wave-uniform (each wave = one chunk:
//     1088 threads/chunk = 17 waves exactly).

typedef float vf2 __attribute__((ext_vector_type(2)));

#define T_DIM 8192
#define C_DIM 51
#define B_DIM 64
#define CHUNK 64
#define HALO 48
#define NCHUNK (T_DIM / CHUNK)   // 128
#define TPR 17                   // threads per row; each owns 3 channels
#define TPCH (B_DIM * TPR)       // 1088 threads per chunk (= 17 waves)
#define BLOCK 64

__device__ __forceinline__ void load12(const float* __restrict__ p,
                                       float& v0, float& v1, float& v2) {
    vf2 v;
    __builtin_memcpy(&v, p, 8);   // align-4 8B load (rows are only 4B-aligned)
    v0 = v[0];
    v1 = v[1];
    v2 = p[2];
}

__device__ __forceinline__ void store12(float* __restrict__ p,
                                        float v0, float v1, float v2) {
    vf2 v;
    v[0] = v0;
    v[1] = v1;
    __builtin_memcpy(p, &v, 8);
    p[2] = v2;
}

__global__ __launch_bounds__(BLOCK) void ema_kernel(const float* __restrict__ x,
                                                    float* __restrict__ y) {
    const int gid = blockIdx.x * BLOCK + threadIdx.x;
    const int chunk = gid / TPCH;
    if (chunk >= NCHUNK) return;           // belt-and-suspenders
    const int r = gid - chunk * TPCH;
    const int b = r / TPR;
    const int j = r - b * TPR;

    const size_t base = (size_t)b * ((size_t)T_DIM * C_DIM) + 3 * j;
    const int t0 = chunk * CHUNK;
    const int tend = t0 + CHUNK;
    const int tstart = (chunk == 0) ? 0 : (t0 - HALO);
    const int tloop = (chunk == 0) ? 0 : (tstart + 1);

    const float* __restrict__ px = x + base + (size_t)tstart * C_DIM;
    float* __restrict__ py = y + base + (size_t)t0 * C_DIM;

    // acc = x[tstart] (halo seed; for chunk 0 this makes y0 exact)
    float a0, a1, a2;
    load12(px, a0, a1, a2);
    px += (size_t)(tloop - tstart) * C_DIM;

    // depth-2 software pipeline: rows tloop, tloop+1 in flight
    float x0a, x0b, x0c, x1a, x1b, x1c;
    load12(px, x0a, x0b, x0c); px += C_DIM;
    load12(px, x1a, x1b, x1c); px += C_DIM;

    int t = tloop;
#pragma unroll 2
    for (; t < tend - 2; ++t) {
        float x2a, x2b, x2c;
        load12(px, x2a, x2b, x2c);         // prefetch row t+2
        px += C_DIM;
        a0 = fmaf(0.75f, a0, 0.25f * x0a); // 1-fma dependent chain per step
        a1 = fmaf(0.75f, a1, 0.25f * x0b);
        a2 = fmaf(0.75f, a2, 0.25f * x0c);
        if (t >= t0) {                     // wave-uniform (s_cmp + skip)
            store12(py, a0, a1, a2);
            py += C_DIM;
        }
        x0a = x1a; x0b = x1b; x0c = x1c;
        x1a = x2a; x1b = x2b; x1c = x2c;
    }
    // epilogue: t = tend-2 (uses x0), t = tend-1 (uses x1); both stored
    a0 = fmaf(0.75f, a0, 0.25f * x0a);
    a1 = fmaf(0.75f, a1, 0.25f * x0b);
    a2 = fmaf(0.75f, a2, 0.25f * x0c);
    store12(py, a0, a1, a2);
    py += C_DIM;
    a0 = fmaf(0.75f, a0, 0.25f * x1a);
    a1 = fmaf(0.75f, a1, 0.25f * x1b);
    a2 = fmaf(0.75f, a2, 0.25f * x1c);
    store12(py, a0, a1, a2);
}

extern "C" void kernel_launch(void* const* d_in, const int* in_sizes, int n_in,
                              void* d_out, int out_size, void* d_ws, size_t ws_size,
                              hipStream_t stream) {
    const float* x = (const float*)d_in[0];
    float* y = (float*)d_out;

    int B = in_sizes[0] / (T_DIM * C_DIM);          // 64 (elements)
    int total_threads = B * TPR * NCHUNK;           // 139264
    int grid = (total_threads + BLOCK - 1) / BLOCK; // 2176 blocks x 64 thr
    ema_kernel<<<grid, BLOCK, 0, stream>>>(x, y);
}

// Round 2
// 198.480 us; speedup vs baseline: 1.1463x; 1.1463x over previous
//
#include <hip/hip_runtime.h>

// EMA along T for pos_seq (B=64, T=8192, C=51) fp32.
// y[b,0,c] = x[b,0,c];  y[b,t,c] = 0.25*x[b,t,c] + 0.75*y[b,t-1,c]
//
// R8: wave-autonomous LDS-transpose streaming scan.
// R7 post-mortem: 12B/lane accesses hit the small-access transaction plateau
// (~2.5 TB/s, guide m18) and depth-2 prefetch left only ~9 KB/CU in flight.
// R6 post-mortem: all-16B traffic but 3 barriers + vmcnt(0) drains serialized
// the phases. R8 = 16B-only HBM traffic (m13 pattern) + zero barriers:
//
//  Block = 1 wave (64 lanes) owns (b, 256-row span). Per 64-row tile:
//   1. issue 13 global_load_dwordx4 per lane for tile k+1 into registers
//      (T14 async-split: 13 KB/wave in flight under compute)
//   2. compute tile k in LDS: lane c (c<51) walks 64 rows,
//      acc = fma(0.75, acc, 0.25*x); row reads are 51 consecutive dwords
//      -> max 2 lanes/bank = conflict-free; results written back in place
//   3. bulk-store tile k as dwordx4 (nontemporal)
//   4. ds_write staged registers -> LDS (compiler's vmcnt wait lands here)
//  No __syncthreads anywhere: single-wave block, in-order LDS pipe per wave.
//
//  Warm-up: spans > 0 prepend one un-stored 64-row tile; seeding acc with
//  x[t0-64] leaves error 0.75^64 ~ 1e-8 by the first stored row (tolerance
//  3.9e-3). Span 0 seeds acc = x[0], so y[0] = 0.25*x0 + 0.75*x0 = x0.
//  Refetch ratio 5/4 -> ~134 MB in + 107 MB out.
//
//  Grid 64*32 = 2048 single-wave blocks; LDS 13 KB -> 12 blocks/CU cap,
//  whole grid co-resident at 8/CU. In-flight capacity ~8*13 KB >> the
//  ~9 KB/CU needed for 6.3 TB/s at ~900 cy HBM latency.

typedef float vf4 __attribute__((ext_vector_type(4)));

#define T_DIM 8192
#define C_DIM 51
#define TILE 64
#define SPAN 256
#define NSPAN (T_DIM / SPAN)   // 32
#define NTILE (SPAN / TILE)    // 4
#define TILE_F (TILE * C_DIM)  // 3264 floats = 13056 B (16B-aligned: 64*204)
#define TILE_V4 (TILE_F / 4)   // 816
#define VPL 13                 // ceil(816/64) dwordx4 per lane

__global__ __launch_bounds__(64) void ema_kernel(const float* __restrict__ x,
                                                 float* __restrict__ y) {
    __shared__ float buf[TILE_F];

    const int lane = threadIdx.x;
    const int sp = blockIdx.x % NSPAN;
    const int b = blockIdx.x / NSPAN;
    const size_t plane = (size_t)b * ((size_t)T_DIM * C_DIM);
    const int t0 = sp * SPAN;
    const bool warm = (sp != 0);
    const int ntiles = warm ? NTILE + 1 : NTILE;
    const int first_row = warm ? (t0 - TILE) : t0;

    const float* __restrict__ xp = x + plane + (size_t)first_row * C_DIM;
    float* __restrict__ yp = y + plane + (size_t)t0 * C_DIM;

    // ---- prologue: stage tile 0 (regs -> LDS) ----
    vf4 st[VPL];
#pragma unroll
    for (int i = 0; i < VPL; ++i) {
        const int j = i * 64 + lane;
        if (j < TILE_V4) st[i] = *(const vf4*)(xp + 4 * j);
    }
#pragma unroll
    for (int i = 0; i < VPL; ++i) {
        const int j = i * 64 + lane;
        if (j < TILE_V4) *(vf4*)(&buf[4 * j]) = st[i];
    }

    // seed: acc = x[first_row, lane]  (exact y0 for span 0; halo seed else)
    float acc = 0.0f;
    if (lane < C_DIM) acc = buf[lane];

    for (int k = 0; k < ntiles; ++k) {
        const bool has_next = (k + 1 < ntiles);

        // ---- 1. issue next tile's loads early (hide under compute) ----
        if (has_next) {
            const float* __restrict__ xn = xp + (size_t)(k + 1) * TILE_F;
#pragma unroll
            for (int i = 0; i < VPL; ++i) {
                const int j = i * 64 + lane;
                if (j < TILE_V4) st[i] = *(const vf4*)(xn + 4 * j);
            }
        }

        // ---- 2. EMA over 64 rows, in place in LDS (lane = channel) ----
        if (lane < C_DIM) {
#pragma unroll
            for (int t = 0; t < TILE; ++t) {
                const float xv = buf[t * C_DIM + lane];
                acc = fmaf(0.75f, acc, 0.25f * xv);
                buf[t * C_DIM + lane] = acc;
            }
        }

        // ---- 3. bulk 16B store of computed tile ----
        const bool stored = (!warm) || (k > 0);
        if (stored) {
            float* __restrict__ yo = yp + (size_t)(warm ? (k - 1) : k) * TILE_F;
#pragma unroll
            for (int i = 0; i < VPL; ++i) {
                const int j = i * 64 + lane;
                if (j < TILE_V4) {
                    vf4 v = *(const vf4*)(&buf[4 * j]);
                    __builtin_nontemporal_store(v, (vf4*)(yo + 4 * j));
                }
            }
        }

        // ---- 4. commit staged regs for next tile (vmcnt wait lands here) ----
        if (has_next) {
#pragma unroll
            for (int i = 0; i < VPL; ++i) {
                const int j = i * 64 + lane;
                if (j < TILE_V4) *(vf4*)(&buf[4 * j]) = st[i];
            }
        }
    }
}

extern "C" void kernel_launch(void* const* d_in, const int* in_sizes, int n_in,
                              void* d_out, int out_size, void* d_ws, size_t ws_size,
                              hipStream_t stream) {
    const float* x = (const float*)d_in[0];
    float* y = (float*)d_out;

    int B = in_sizes[0] / (T_DIM * C_DIM);  // 64
    int grid = B * NSPAN;                   // 2048 single-wave blocks
    ema_kernel<<<grid, 64, 0, stream>>>(x, y);
}

// Round 3
// 197.619 us; speedup vs baseline: 1.1513x; 1.0044x over previous
//
#include <hip/hip_runtime.h>

// EMA along T for pos_seq (B=64, T=8192, C=51) fp32.
// y[b,0,c] = x[b,0,c];  y[b,t,c] = 0.25*x[b,t,c] + 0.75*y[b,t-1,c]
//
// R9: R8 structure (wave-autonomous, barrier-free, 16B-only HBM traffic)
// with the compute phase rebuilt. R8 post-mortem: the in-place LDS scan
// (ds_read -> fma -> ds_write, same buffer) forced per-row lgkmcnt drains
// (~300 cy/row, ~20k cy/tile) during which the wave had ZERO bytes in
// flight -> per-CU outstanding collapsed to ~10 KB -> Little's law gives the
// observed 2.3 TB/s. Fix: separate the LDS->reg transpose from the scan:
//   xv[0..63] <- 64 independent ds_read_b32 (one fine-grained wait, ~370 cy)
//   acc chain in registers (64 fma, ~256 cy) with ds_writes alongside
//     (WAR on the in-order per-wave LDS pipe needs no waits)
// Per-tile serial work drops ~20k -> ~1.5k cy; the wave then parks on the
// phase-4 vmcnt wait WITH its 13 KB of next-tile loads outstanding.
// 8 waves/CU x 13 KB ~ 100 KB in flight sustained >> ~10 B/cy/CU for 6.3 TB/s.
//
//  Block = 1 wave (64 lanes) owns (b, 256-row span). Per 64-row tile:
//   1. issue 13 global_load_dwordx4 (tile k+1) into st[] registers
//   2. transpose buf -> xv[64] regs; register EMA chain; results -> buf
//   3. bulk 16B nontemporal store of tile k
//   4. commit st[] -> buf (compiler's vmcnt(13) wait lands here: waits only
//      the loads, not the just-issued stores)
//  No __syncthreads anywhere (single-wave block, in-order LDS pipe).
//
//  Warm-up: spans > 0 prepend one un-stored 64-row tile; seed acc = x[t0-64]
//  leaves error 0.75^64 ~ 1e-8 by the first stored row. Span 0 seeds
//  acc = x[0] so y[0] = 0.25*x0 + 0.75*x0 = x0 (1 ulp).
//
//  Grid 64*32 = 2048 single-wave blocks, 8/CU co-resident (LDS 13 KB).

typedef float vf4 __attribute__((ext_vector_type(4)));

#define T_DIM 8192
#define C_DIM 51
#define TILE 64
#define SPAN 256
#define NSPAN (T_DIM / SPAN)   // 32
#define NTILE (SPAN / TILE)    // 4
#define TILE_F (TILE * C_DIM)  // 3264 floats = 13056 B (16B-aligned: 64*204)
#define TILE_V4 (TILE_F / 4)   // 816
#define VPL 13                 // ceil(816/64) dwordx4 per lane

__global__ __launch_bounds__(64) void ema_kernel(const float* __restrict__ x,
                                                 float* __restrict__ y) {
    __shared__ float buf[TILE_F];

    const int lane = threadIdx.x;
    const int sp = blockIdx.x % NSPAN;
    const int b = blockIdx.x / NSPAN;
    const size_t plane = (size_t)b * ((size_t)T_DIM * C_DIM);
    const int t0 = sp * SPAN;
    const bool warm = (sp != 0);
    const int ntiles = warm ? NTILE + 1 : NTILE;
    const int first_row = warm ? (t0 - TILE) : t0;

    const float* __restrict__ xp = x + plane + (size_t)first_row * C_DIM;
    float* __restrict__ yp = y + plane + (size_t)t0 * C_DIM;

    // ---- prologue: stage tile 0 (regs -> LDS) ----
    vf4 st[VPL];
#pragma unroll
    for (int i = 0; i < VPL; ++i) {
        const int j = i * 64 + lane;
        if (j < TILE_V4) st[i] = *(const vf4*)(xp + 4 * j);
    }
#pragma unroll
    for (int i = 0; i < VPL; ++i) {
        const int j = i * 64 + lane;
        if (j < TILE_V4) *(vf4*)(&buf[4 * j]) = st[i];
    }

    // seed: acc = x[first_row, lane]  (exact y0 for span 0; halo seed else)
    float acc = 0.0f;
    if (lane < C_DIM) acc = buf[lane];

    for (int k = 0; k < ntiles; ++k) {
        const bool has_next = (k + 1 < ntiles);

        // ---- 1. issue next tile's loads early (hide under compute) ----
        if (has_next) {
            const float* __restrict__ xn = xp + (size_t)(k + 1) * TILE_F;
#pragma unroll
            for (int i = 0; i < VPL; ++i) {
                const int j = i * 64 + lane;
                if (j < TILE_V4) st[i] = *(const vf4*)(xn + 4 * j);
            }
        }

        // ---- 2. transpose to regs, register EMA chain, write back ----
        if (lane < C_DIM) {
            float xv[TILE];
#pragma unroll
            for (int t = 0; t < TILE; ++t)
                xv[t] = buf[t * C_DIM + lane];     // 64 independent ds_read
#pragma unroll
            for (int t = 0; t < TILE; ++t) {
                acc = fmaf(0.75f, acc, 0.25f * xv[t]);  // pure-reg chain
                buf[t * C_DIM + lane] = acc;            // WAR: no wait needed
            }
        }

        // ---- 3. bulk 16B store of computed tile ----
        const bool stored = (!warm) || (k > 0);
        if (stored) {
            float* __restrict__ yo = yp + (size_t)(warm ? (k - 1) : k) * TILE_F;
#pragma unroll
            for (int i = 0; i < VPL; ++i) {
                const int j = i * 64 + lane;
                if (j < TILE_V4) {
                    vf4 v = *(const vf4*)(&buf[4 * j]);
                    __builtin_nontemporal_store(v, (vf4*)(yo + 4 * j));
                }
            }
        }

        // ---- 4. commit staged regs for next tile (vmcnt wait lands here) ----
        if (has_next) {
#pragma unroll
            for (int i = 0; i < VPL; ++i) {
                const int j = i * 64 + lane;
                if (j < TILE_V4) *(vf4*)(&buf[4 * j]) = st[i];
            }
        }
    }
}

extern "C" void kernel_launch(void* const* d_in, const int* in_sizes, int n_in,
                              void* d_out, int out_size, void* d_ws, size_t ws_size,
                              hipStream_t stream) {
    const float* x = (const float*)d_in[0];
    float* y = (float*)d_out;

    int B = in_sizes[0] / (T_DIM * C_DIM);  // 64
    int grid = B * NSPAN;                   // 2048 single-wave blocks
    ema_kernel<<<grid, 64, 0, stream>>>(x, y);
}